// Round 10
// baseline (609.497 us; speedup 1.0000x reference)
//
#include <hip/hip_runtime.h>
#include <hip/hip_bf16.h>

#define N_NODES 100000
#define F_IN    256
#define H_DIM   128
#define C_CLS   16
#define NB_SCAN ((N_NODES + 255) / 256)   // 391
#define NSHARD  8
#define SHARD_W ((N_NODES + NSHARD - 1) / NSHARD)   // 12500
#define CHUNK_E 4096

typedef __attribute__((ext_vector_type(8))) short  short8;
typedef __attribute__((ext_vector_type(4))) float  float4v;
typedef __attribute__((ext_vector_type(4))) unsigned short ushort4v;

__device__ __forceinline__ float b2f(ushort u) {
    union { unsigned int i; float f; } v;
    v.i = ((unsigned int)u) << 16;
    return v.f;
}

__device__ __forceinline__ ushort f2b(float f) {
    unsigned int x = __float_as_uint(f);
    unsigned int r = (x + 0x7FFFu + ((x >> 16) & 1u)) >> 16;   // RNE
    return (ushort)r;
}

__device__ __forceinline__ float ldsel(const void* p, int i, int f32f) {
    return f32f ? ((const float*)p)[i] : b2f(((const ushort*)p)[i]);
}

// ------------------------------------------------------------------ sniff ---
__global__ __launch_bounds__(64) void sniff(const ushort* __restrict__ x,
                                            const int* __restrict__ ei,
                                            int* __restrict__ flags) {
    int lane = threadIdx.x;
    int cnt_bf = 0;
#pragma unroll
    for (int j = 0; j < 4; ++j) {
        ushort u = x[lane * 4 + j];
        int e = (u >> 7) & 0xFF;
        if ((e >= 100 && e <= 140) || (u & 0x7FFF) == 0) cnt_bf++;
    }
    int zodd = (ei[2 * lane + 1] == 0) ? 1 : 0;
#pragma unroll
    for (int off = 32; off >= 1; off >>= 1) {
        cnt_bf += __shfl_xor(cnt_bf, off, 64);
        zodd   += __shfl_xor(zodd,   off, 64);
    }
    if (lane == 0) {
        flags[0] = (cnt_bf < 230) ? 1 : 0;   // f32 inputs
        flags[1] = (zodd  >= 32) ? 1 : 0;    // int64 indices
    }
}

// ---------------- merged param prep: wtg = W^T  +  bayes weights ------------
__global__ __launch_bounds__(256) void prep_params(const int* __restrict__ flags,
                                                   const void* __restrict__ W_any,
                                                   ushort* __restrict__ wtg,
                                                   const void* __restrict__ w_mu,
                                                   const void* __restrict__ w_ls,
                                                   const void* __restrict__ eps_w,
                                                   const void* __restrict__ b_mu,
                                                   const void* __restrict__ b_ls,
                                                   const void* __restrict__ eps_b,
                                                   const void* __restrict__ gcn_b,
                                                   ushort* __restrict__ whi,
                                                   ushort* __restrict__ wlo,
                                                   float* __restrict__ bias16,
                                                   float* __restrict__ gcnb_f) {
    const int f32f = flags[0];
    const int t = threadIdx.x;
    if (blockIdx.x < H_DIM) {
        const int n = blockIdx.x;      // 0..127
        float v = f32f ? ((const float*)W_any)[t * H_DIM + n]
                       : b2f(((const ushort*)W_any)[t * H_DIM + n]);
        wtg[n * F_IN + t] = f2b(v);
        return;
    }
#pragma unroll
    for (int i = t; i < C_CLS * H_DIM; i += 256) {
        float v = ldsel(w_mu, i, f32f) + __expf(ldsel(w_ls, i, f32f)) * ldsel(eps_w, i, f32f);
        ushort h = f2b(v);
        whi[i] = h;
        wlo[i] = f2b(v - b2f(h));     // residual: recovers ~16-bit mantissa
    }
    if (t < C_CLS)
        bias16[t] = ldsel(b_mu, t, f32f) + __expf(ldsel(b_ls, t, f32f)) * ldsel(eps_b, t, f32f);
    if (t < H_DIM)
        gcnb_f[t] = ldsel(gcn_b, t, f32f);
}

// ------------- prep: degree count + compact (src,dst) pair array ------------
__global__ __launch_bounds__(256) void prep(const int* __restrict__ flags,
                                            const int* __restrict__ ei,
                                            int* __restrict__ cnt,
                                            int2* __restrict__ pr, int E) {
    int e = blockIdx.x * 256 + threadIdx.x;
    if (e >= E) return;
    int i64 = flags[1];
    int s = i64 ? ei[2L * e]          : ei[e];
    int d = i64 ? ei[2L * E + 2L * e] : ei[(long)E + e];
    pr[e] = make_int2(s, d);
    atomicAdd(&cnt[d], 1);
}

// ------------------------------------------------------------ 3-step scan ---
__global__ __launch_bounds__(256) void scan1(const int* __restrict__ cnt,
                                             int* __restrict__ offs,
                                             int* __restrict__ bsum) {
    __shared__ int sd[256];
    int t = threadIdx.x;
    int i = blockIdx.x * 256 + t;
    int v = (i < N_NODES) ? cnt[i] : 0;
    sd[t] = v;
    __syncthreads();
#pragma unroll
    for (int d = 1; d < 256; d <<= 1) {
        int add = (t >= d) ? sd[t - d] : 0;
        __syncthreads();
        sd[t] += add;
        __syncthreads();
    }
    if (i < N_NODES) offs[i] = sd[t] - v;          // exclusive within block
    if (t == 255) bsum[blockIdx.x] = sd[255];
}

__global__ __launch_bounds__(512) void scan2(const int* __restrict__ bsum,
                                             int* __restrict__ boff) {
    __shared__ int sd[512];
    int t = threadIdx.x;
    int v = (t < NB_SCAN) ? bsum[t] : 0;
    sd[t] = v;
    __syncthreads();
#pragma unroll
    for (int d = 1; d < 512; d <<= 1) {
        int add = (t >= d) ? sd[t - d] : 0;
        __syncthreads();
        sd[t] += add;
        __syncthreads();
    }
    if (t < NB_SCAN) boff[t] = sd[t] - v;          // exclusive
}

// offs -> global offsets; also cursor copy and dis = rsqrt(deg) fused
__global__ __launch_bounds__(256) void scan3(int* __restrict__ offs,
                                             const int* __restrict__ boff,
                                             const int* __restrict__ cnt,
                                             int* __restrict__ cursor,
                                             float* __restrict__ dis, int E) {
    int i = blockIdx.x * 256 + threadIdx.x;
    if (i == 0) offs[N_NODES] = E;
    if (i >= N_NODES) return;
    int off = offs[i] + boff[i >> 8];
    offs[i] = off;
    cursor[i] = off;
    dis[i] = rsqrtf((float)(cnt[i] + 1));          // +1 self-loop
}

// ---------------------- XCD-verified sharded permutation build --------------
// Round-9 post-mortem: fusing scatter with gemm regressed (LDS/VGPR footprint
// cut scatter occupancy 76->20%). Reverted. This round tests the LAST
// unverified premise of the sharding scheme: that blockIdx%8 == XCD. Here the
// shard is derived from the PHYSICAL die id (s_getreg HW_REG_XCC_ID, m09),
// so each XCD's scatter window (800KB perm + 50KB cursor) is guaranteed
// L2-private. Blocks self-distribute via per-shard chunk counters wc[8]
// (one global atomic per 4096-edge chunk). After draining its own shard each
// block steals any unfinished shard -- completeness is guaranteed even if
// the XCC distribution is skewed; stealing is a no-op when healthy.
__global__ __launch_bounds__(256) void build_perm(const int2* __restrict__ pr,
                                                  int* __restrict__ cursor,
                                                  int* __restrict__ perm,
                                                  int* __restrict__ wc, int E) {
    __shared__ int sbase;
    unsigned xcc;
    asm volatile("s_getreg_b32 %0, hwreg(HW_REG_XCC_ID)" : "=s"(xcc));
    const int myshard = (int)(xcc & (NSHARD - 1));
    const int t = threadIdx.x;

    for (int r = 0; r < NSHARD; ++r) {
        const int sh = (myshard + r) & (NSHARD - 1);
        const int lo = sh * SHARD_W;
        const int hi = lo + SHARD_W;               // N divides evenly
        for (;;) {
            if (t == 0) sbase = atomicAdd(&wc[sh], 1);
            __syncthreads();
            const long base = (long)sbase * CHUNK_E;
            __syncthreads();                        // all read before next write
            if (base >= E) break;                   // uniform exit
            long end = base + CHUNK_E; if (end > E) end = E;
            for (long e = base + t; e < end; e += 256) {
                int2 p = pr[e];
                if (p.y >= lo && p.y < hi) {
                    int slot = atomicAdd(&cursor[p.y], 1);
                    perm[slot] = p.x;
                }
            }
        }
    }
}

// ------------------------------------------------- h' = (x @ W) * dis -------
// M=32 per wave (two A-frags share each B ds_read -> 2 MFMAs per b128 read).
// Block = 4 waves = 128 rows -> grid 782 <= resident blocks: no tail round.
// XOR-swizzled flat LDS: idx = ((col<<7)|k) ^ ((col&7)<<3).
__global__ __launch_bounds__(256) void gemm_xw(const int* __restrict__ flags,
                                               const void* __restrict__ x_any,
                                               const ushort* __restrict__ wtg,
                                               const float* __restrict__ dis,
                                               ushort* __restrict__ hout) {
    __shared__ __align__(16) ushort wt[128 * 128];      // 32768 B
    const int f32f = flags[0];

    const int tid  = threadIdx.x;
    const int lane = tid & 63;
    const int quad = lane >> 4;
    const int lm   = lane & 15;
    const int wave = tid >> 6;

    const int rbase = blockIdx.x * 128 + wave * 32;
    int arow0 = rbase + lm;
    int arow1 = rbase + 16 + lm;
    if (arow0 >= N_NODES) arow0 = N_NODES - 1;    // clamp; store is guarded
    if (arow1 >= N_NODES) arow1 = N_NODES - 1;
    const float*  xrf0 = (const float*) x_any + (size_t)arow0 * F_IN;
    const float*  xrf1 = (const float*) x_any + (size_t)arow1 * F_IN;
    const ushort* xrb0 = (const ushort*)x_any + (size_t)arow0 * F_IN;
    const ushort* xrb1 = (const ushort*)x_any + (size_t)arow1 * F_IN;

    float4v acc0[8], acc1[8];
#pragma unroll
    for (int c = 0; c < 8; ++c) {
        acc0[c] = (float4v){0.f, 0.f, 0.f, 0.f};
        acc1[c] = (float4v){0.f, 0.f, 0.f, 0.f};
    }

    for (int hh = 0; hh < 2; ++hh) {
        if (hh) __syncthreads();
#pragma unroll
        for (int it = 0; it < 8; ++it) {
            int flat = (it * 256 + tid) * 8;       // ushort idx, 0..16376
            int col  = flat >> 7;
            int kloc = flat & 127;
            short8 v = *(const short8*)(wtg + col * F_IN + hh * 128 + kloc);
            int dst = ((col << 7) | kloc) ^ ((col & 7) << 3);
            *(short8*)(wt + dst) = v;
        }
        __syncthreads();
#pragma unroll
        for (int s = 0; s < 4; ++s) {
            int klocal = s * 32 + quad * 8;
            short8 afrag0, afrag1;
            if (f32f) {
                const float* p0 = xrf0 + hh * 128 + klocal;
                const float* p1 = xrf1 + hh * 128 + klocal;
                float4 u0 = *(const float4*)p0;
                float4 u1 = *(const float4*)(p0 + 4);
                float4 u2 = *(const float4*)p1;
                float4 u3 = *(const float4*)(p1 + 4);
                afrag0[0] = (short)f2b(u0.x); afrag0[1] = (short)f2b(u0.y);
                afrag0[2] = (short)f2b(u0.z); afrag0[3] = (short)f2b(u0.w);
                afrag0[4] = (short)f2b(u1.x); afrag0[5] = (short)f2b(u1.y);
                afrag0[6] = (short)f2b(u1.z); afrag0[7] = (short)f2b(u1.w);
                afrag1[0] = (short)f2b(u2.x); afrag1[1] = (short)f2b(u2.y);
                afrag1[2] = (short)f2b(u2.z); afrag1[3] = (short)f2b(u2.w);
                afrag1[4] = (short)f2b(u3.x); afrag1[5] = (short)f2b(u3.y);
                afrag1[6] = (short)f2b(u3.z); afrag1[7] = (short)f2b(u3.w);
            } else {
                afrag0 = *(const short8*)(xrb0 + hh * 128 + klocal);
                afrag1 = *(const short8*)(xrb1 + hh * 128 + klocal);
            }
#pragma unroll
            for (int c = 0; c < 8; ++c) {
                int colr = c * 16 + lm;
                int src = ((colr << 7) | klocal) ^ ((lm & 7) << 3);
                short8 bfrag = *(const short8*)(wt + src);
                acc0[c] = __builtin_amdgcn_mfma_f32_16x16x32_bf16(afrag0, bfrag, acc0[c], 0, 0, 0);
                acc1[c] = __builtin_amdgcn_mfma_f32_16x16x32_bf16(afrag1, bfrag, acc1[c], 0, 0, 0);
            }
        }
    }
    // D[row=quad*4+r][col=lane&15]; scale rows by dis[node] before rounding
    float dv0[4], dv1[4];
#pragma unroll
    for (int r = 0; r < 4; ++r) {
        int n0 = rbase + quad * 4 + r;
        int n1 = rbase + 16 + quad * 4 + r;
        dv0[r] = (n0 < N_NODES) ? dis[n0] : 0.f;
        dv1[r] = (n1 < N_NODES) ? dis[n1] : 0.f;
    }
#pragma unroll
    for (int c = 0; c < 8; ++c) {
        int col = c * 16 + lm;
#pragma unroll
        for (int r = 0; r < 4; ++r) {
            int n0 = rbase + quad * 4 + r;
            int n1 = rbase + 16 + quad * 4 + r;
            if (n0 < N_NODES) hout[(size_t)n0 * H_DIM + col] = f2b(acc0[c][r] * dv0[r]);
            if (n1 < N_NODES) hout[(size_t)n1 * H_DIM + col] = f2b(acc1[c][r] * dv1[r]);
        }
    }
}

// --------------------- gather-reduce + bias + relu -> a (bf16) --------------
__global__ __launch_bounds__(256) void gather_relu(const int* __restrict__ offs,
                                                   const int* __restrict__ perm,
                                                   const float* __restrict__ dis,
                                                   const ushort* __restrict__ hb,
                                                   const float* __restrict__ gcnb_f,
                                                   ushort* __restrict__ aout) {
    const int lane = threadIdx.x & 63;
    const int node = blockIdx.x * 4 + (threadIdx.x >> 6);
    if (node >= N_NODES) return;

    const int off0 = __builtin_amdgcn_readfirstlane(offs[node]);
    const int deg  = __builtin_amdgcn_readfirstlane(offs[node + 1]) - off0;
    const int* pp = perm + off0;

    float ax = 0.f, ay = 0.f;
    const int full = deg & ~15;
    for (int base = 0; base < full; base += 16) {
#pragma unroll
        for (int k = 0; k < 16; ++k) {
            int sk = pp[base + k];                  // scalar 4B load (uniform)
            uint u = *((const uint*)(hb + (size_t)sk * H_DIM) + lane);
            ax += __uint_as_float(u << 16);
            ay += __uint_as_float(u & 0xFFFF0000u);
        }
    }
    {
        const int nb = deg - full;                  // 0..15, uniform
#pragma unroll
        for (int k = 0; k < 16; ++k) {
            int   sk = 0;
            float wk = 0.f;
            if (k < nb) { sk = pp[full + k]; wk = 1.f; }
            uint u = *((const uint*)(hb + (size_t)sk * H_DIM) + lane);
            ax = fmaf(wk, __uint_as_float(u << 16),         ax);
            ay = fmaf(wk, __uint_as_float(u & 0xFFFF0000u), ay);
        }
    }

    const float dd = dis[node];
    uint us = *((const uint*)(hb + (size_t)node * H_DIM) + lane);   // h'[node]
    float2 gb = *(const float2*)(gcnb_f + 2 * lane);
    ax = (ax + __uint_as_float(us << 16))         * dd + gb.x;
    ay = (ay + __uint_as_float(us & 0xFFFF0000u)) * dd + gb.y;
    ax = fmaxf(ax, 0.f);
    ay = fmaxf(ay, 0.f);
    uint pack = (uint)f2b(ax) | ((uint)f2b(ay) << 16);
    *((uint*)(aout + (size_t)node * H_DIM) + lane) = pack;
}

// -------------------- logits = a @ w^T + b, then log_softmax ----------------
__global__ __launch_bounds__(256) void final_linear(const int* __restrict__ flags,
                                                    const ushort* __restrict__ a,
                                                    const ushort* __restrict__ whi,
                                                    const ushort* __restrict__ wlo,
                                                    const float* __restrict__ bias16,
                                                    void* __restrict__ out) {
    const int f32f = flags[0];
    const int lane = threadIdx.x & 63;
    const int wave = threadIdx.x >> 6;
    const int n0 = (blockIdx.x * 4 + wave) * 16;
    if (n0 >= N_NODES) return;                 // 16 | N_NODES, no partial wave
    const int lm = lane & 15, quad = lane >> 4;

    const ushort* arow = a   + (size_t)(n0 + lm) * H_DIM + quad * 8;
    const ushort* bh   = whi + lm * H_DIM + quad * 8;
    const ushort* bl   = wlo + lm * H_DIM + quad * 8;

    float4v acc = (float4v){0.f, 0.f, 0.f, 0.f};
#pragma unroll
    for (int s = 0; s < 4; ++s) {
        short8 af = *(const short8*)(arow + s * 32);
        short8 b0 = *(const short8*)(bh   + s * 32);
        short8 b1 = *(const short8*)(bl   + s * 32);
        acc = __builtin_amdgcn_mfma_f32_16x16x32_bf16(af, b0, acc, 0, 0, 0);
        acc = __builtin_amdgcn_mfma_f32_16x16x32_bf16(af, b1, acc, 0, 0, 0);
    }

    const float bias = bias16[lm];
    float p[4], m[4], ss[4];
#pragma unroll
    for (int r = 0; r < 4; ++r) { p[r] = acc[r] + bias; m[r] = p[r]; }
#pragma unroll
    for (int off = 1; off < 16; off <<= 1)
#pragma unroll
        for (int r = 0; r < 4; ++r) m[r] = fmaxf(m[r], __shfl_xor(m[r], off, 64));
#pragma unroll
    for (int r = 0; r < 4; ++r) ss[r] = __expf(p[r] - m[r]);
#pragma unroll
    for (int off = 1; off < 16; off <<= 1)
#pragma unroll
        for (int r = 0; r < 4; ++r) ss[r] += __shfl_xor(ss[r], off, 64);

    if (f32f) {
        float* op = (float*)out;
#pragma unroll
        for (int r = 0; r < 4; ++r)
            op[(size_t)(n0 + quad * 4 + r) * C_CLS + lm] = p[r] - m[r] - __logf(ss[r]);
    } else {
        ushort* op = (ushort*)out;
#pragma unroll
        for (int r = 0; r < 4; ++r)
            op[(size_t)(n0 + quad * 4 + r) * C_CLS + lm] = f2b(p[r] - m[r] - __logf(ss[r]));
    }
}

// ---------------------------------------------------------------------------
extern "C" void kernel_launch(void* const* d_in, const int* in_sizes, int n_in,
                              void* d_out, int out_size, void* d_ws, size_t ws_size,
                              hipStream_t stream) {
    const int E = in_sizes[1] / 2;

    char* wp = (char*)d_ws;
    auto alloc = [&](size_t bytes) -> char* {
        char* p = wp; wp += (bytes + 511) & ~(size_t)511; return p;
    };
    int*    flags  = (int*)   alloc(64);
    ushort* hb     = (ushort*)alloc((size_t)N_NODES * H_DIM * 2);   // bf16 h*dis
    ushort* aout   = (ushort*)alloc((size_t)N_NODES * H_DIM * 2);   // bf16 relu(agg)
    int*    cnt    = (int*)   alloc((size_t)N_NODES * 4);
    int*    offs   = (int*)   alloc((size_t)(N_NODES + 1) * 4);
    int*    cursor = (int*)   alloc((size_t)N_NODES * 4);
    int*    bsum   = (int*)   alloc((size_t)NB_SCAN * 4);
    int*    boff   = (int*)   alloc((size_t)NB_SCAN * 4);
    float*  dis    = (float*) alloc((size_t)N_NODES * 4);
    int*    perm   = (int*)   alloc((size_t)E * 4);                 // src only
    int2*   pr     = (int2*)  alloc((size_t)E * 8);                 // (s,d) compact
    int*    wc     = (int*)   alloc(64);                            // shard chunk ctrs
    ushort* wtg    = (ushort*)alloc((size_t)H_DIM * F_IN * 2);      // W^T bf16
    ushort* whi    = (ushort*)alloc((size_t)C_CLS * H_DIM * 2);
    ushort* wlo    = (ushort*)alloc((size_t)C_CLS * H_DIM * 2);
    float*  bias16 = (float*) alloc((size_t)C_CLS * 4);
    float*  gcnb_f = (float*) alloc((size_t)H_DIM * 4);

    sniff<<<1, 64, 0, stream>>>((const ushort*)d_in[0], (const int*)d_in[1], flags);
    prep_params<<<H_DIM + 1, 256, 0, stream>>>(flags, d_in[2], wtg,
                                  d_in[4], d_in[5], d_in[8],
                                  d_in[6], d_in[7], d_in[9], d_in[3],
                                  whi, wlo, bias16, gcnb_f);
    (void)hipMemsetAsync(cnt, 0, (size_t)N_NODES * 4, stream);
    (void)hipMemsetAsync(wc, 0, 64, stream);
    prep<<<(E + 255) / 256, 256, 0, stream>>>(flags, (const int*)d_in[1], cnt, pr, E);
    scan1<<<NB_SCAN, 256, 0, stream>>>(cnt, offs, bsum);
    scan2<<<1, 512, 0, stream>>>(bsum, boff);
    scan3<<<NB_SCAN, 256, 0, stream>>>(offs, boff, cnt, cursor, dis, E);
    build_perm<<<2048, 256, 0, stream>>>(pr, cursor, perm, wc, E);
    gemm_xw<<<(N_NODES + 127) / 128, 256, 0, stream>>>(flags, d_in[0], wtg, dis, hb);
    gather_relu<<<(N_NODES + 3) / 4, 256, 0, stream>>>(offs, perm, dis, hb, gcnb_f, aout);
    final_linear<<<(N_NODES / C_CLS + 3) / 4, 256, 0, stream>>>(flags, aout, whi, wlo, bias16, (void*)d_out);
}

// Round 11
// 405.148 us; speedup vs baseline: 1.5044x; 1.5044x over previous
//
#include <hip/hip_runtime.h>
#include <hip/hip_bf16.h>

#define N_NODES 100000
#define F_IN    256
#define H_DIM   128
#define C_CLS   16
#define NB_SCAN ((N_NODES + 255) / 256)   // 391
#define NSHARD  8
#define SHARD_W ((N_NODES + NSHARD - 1) / NSHARD)   // 12500

typedef __attribute__((ext_vector_type(8))) short  short8;
typedef __attribute__((ext_vector_type(4))) float  float4v;
typedef __attribute__((ext_vector_type(4))) unsigned short ushort4v;

__device__ __forceinline__ float b2f(ushort u) {
    union { unsigned int i; float f; } v;
    v.i = ((unsigned int)u) << 16;
    return v.f;
}

__device__ __forceinline__ ushort f2b(float f) {
    unsigned int x = __float_as_uint(f);
    unsigned int r = (x + 0x7FFFu + ((x >> 16) & 1u)) >> 16;   // RNE
    return (ushort)r;
}

__device__ __forceinline__ float ldsel(const void* p, int i, int f32f) {
    return f32f ? ((const float*)p)[i] : b2f(((const ushort*)p)[i]);
}

// ------------------------------------------------------------------ sniff ---
__global__ __launch_bounds__(64) void sniff(const ushort* __restrict__ x,
                                            const int* __restrict__ ei,
                                            int* __restrict__ flags) {
    int lane = threadIdx.x;
    int cnt_bf = 0;
#pragma unroll
    for (int j = 0; j < 4; ++j) {
        ushort u = x[lane * 4 + j];
        int e = (u >> 7) & 0xFF;
        if ((e >= 100 && e <= 140) || (u & 0x7FFF) == 0) cnt_bf++;
    }
    int zodd = (ei[2 * lane + 1] == 0) ? 1 : 0;
#pragma unroll
    for (int off = 32; off >= 1; off >>= 1) {
        cnt_bf += __shfl_xor(cnt_bf, off, 64);
        zodd   += __shfl_xor(zodd,   off, 64);
    }
    if (lane == 0) {
        flags[0] = (cnt_bf < 230) ? 1 : 0;   // f32 inputs
        flags[1] = (zodd  >= 32) ? 1 : 0;    // int64 indices
    }
}

// ---------------- merged param prep: wtg = W^T  +  bayes weights ------------
__global__ __launch_bounds__(256) void prep_params(const int* __restrict__ flags,
                                                   const void* __restrict__ W_any,
                                                   ushort* __restrict__ wtg,
                                                   const void* __restrict__ w_mu,
                                                   const void* __restrict__ w_ls,
                                                   const void* __restrict__ eps_w,
                                                   const void* __restrict__ b_mu,
                                                   const void* __restrict__ b_ls,
                                                   const void* __restrict__ eps_b,
                                                   const void* __restrict__ gcn_b,
                                                   ushort* __restrict__ whi,
                                                   ushort* __restrict__ wlo,
                                                   float* __restrict__ bias16,
                                                   float* __restrict__ gcnb_f) {
    const int f32f = flags[0];
    const int t = threadIdx.x;
    if (blockIdx.x < H_DIM) {
        const int n = blockIdx.x;      // 0..127
        float v = f32f ? ((const float*)W_any)[t * H_DIM + n]
                       : b2f(((const ushort*)W_any)[t * H_DIM + n]);
        wtg[n * F_IN + t] = f2b(v);
        return;
    }
#pragma unroll
    for (int i = t; i < C_CLS * H_DIM; i += 256) {
        float v = ldsel(w_mu, i, f32f) + __expf(ldsel(w_ls, i, f32f)) * ldsel(eps_w, i, f32f);
        ushort h = f2b(v);
        whi[i] = h;
        wlo[i] = f2b(v - b2f(h));     // residual: recovers ~16-bit mantissa
    }
    if (t < C_CLS)
        bias16[t] = ldsel(b_mu, t, f32f) + __expf(ldsel(b_ls, t, f32f)) * ldsel(eps_b, t, f32f);
    if (t < H_DIM)
        gcnb_f[t] = ldsel(gcn_b, t, f32f);
}

// ------------- prep: degree count + compact (src,dst) pair array ------------
__global__ __launch_bounds__(256) void prep(const int* __restrict__ flags,
                                            const int* __restrict__ ei,
                                            int* __restrict__ cnt,
                                            int2* __restrict__ pr, int E) {
    int e = blockIdx.x * 256 + threadIdx.x;
    if (e >= E) return;
    int i64 = flags[1];
    int s = i64 ? ei[2L * e]          : ei[e];
    int d = i64 ? ei[2L * E + 2L * e] : ei[(long)E + e];
    pr[e] = make_int2(s, d);
    atomicAdd(&cnt[d], 1);
}

// ------------------------------------------------------------ 3-step scan ---
__global__ __launch_bounds__(256) void scan1(const int* __restrict__ cnt,
                                             int* __restrict__ offs,
                                             int* __restrict__ bsum) {
    __shared__ int sd[256];
    int t = threadIdx.x;
    int i = blockIdx.x * 256 + t;
    int v = (i < N_NODES) ? cnt[i] : 0;
    sd[t] = v;
    __syncthreads();
#pragma unroll
    for (int d = 1; d < 256; d <<= 1) {
        int add = (t >= d) ? sd[t - d] : 0;
        __syncthreads();
        sd[t] += add;
        __syncthreads();
    }
    if (i < N_NODES) offs[i] = sd[t] - v;          // exclusive within block
    if (t == 255) bsum[blockIdx.x] = sd[255];
}

__global__ __launch_bounds__(512) void scan2(const int* __restrict__ bsum,
                                             int* __restrict__ boff) {
    __shared__ int sd[512];
    int t = threadIdx.x;
    int v = (t < NB_SCAN) ? bsum[t] : 0;
    sd[t] = v;
    __syncthreads();
#pragma unroll
    for (int d = 1; d < 512; d <<= 1) {
        int add = (t >= d) ? sd[t - d] : 0;
        __syncthreads();
        sd[t] += add;
        __syncthreads();
    }
    if (t < NB_SCAN) boff[t] = sd[t] - v;          // exclusive
}

// offs -> global offsets; also cursor copy and dis = rsqrt(deg) fused
__global__ __launch_bounds__(256) void scan3(int* __restrict__ offs,
                                             const int* __restrict__ boff,
                                             const int* __restrict__ cnt,
                                             int* __restrict__ cursor,
                                             float* __restrict__ dis, int E) {
    int i = blockIdx.x * 256 + threadIdx.x;
    if (i == 0) offs[N_NODES] = E;
    if (i >= N_NODES) return;
    int off = offs[i] + boff[i >> 8];
    offs[i] = off;
    cursor[i] = off;
    dis[i] = rsqrtf((float)(cnt[i] + 1));          // +1 self-loop
}

// ---------------------------------- XCD-sharded permutation build -----------
// FINAL FORM (round-10 verdict): direct scatter with static shard =
// blockIdx&7. Five attacks on the ~70us cost all failed or regressed
// (payload 8B->4B, nt-loads, compact-pr diet, LDS binning 2x slower,
// XCC_ID-derived shards + stealing 3.8x slower via cross-die RMW ping-pong).
// The kernel is at its read-for-ownership/atomic floor on this memory system.
__global__ __launch_bounds__(256) void build_perm(const int2* __restrict__ pr,
                                                  int* __restrict__ cursor,
                                                  int* __restrict__ perm, int E) {
    const int shard = blockIdx.x & (NSHARD - 1);
    const int jb    = blockIdx.x >> 3;
    const int nb    = gridDim.x >> 3;
    const int lo = shard * SHARD_W;
    const int hi = lo + SHARD_W;                 // N divides evenly
    for (int e = jb * 256 + threadIdx.x; e < E; e += nb * 256) {
        int2 p = pr[e];
        if (p.y >= lo && p.y < hi) {
            int slot = atomicAdd(&cursor[p.y], 1);
            perm[slot] = p.x;
        }
    }
}

// ------------------------------------------------- h' = (x @ W) * dis -------
// M=32 per wave (two A-frags share each B ds_read -> 2 MFMAs per b128 read).
// Block = 4 waves = 128 rows -> grid 782 <= resident blocks: no tail round.
// XOR-swizzled flat LDS: idx = ((col<<7)|k) ^ ((col&7)<<3).
__global__ __launch_bounds__(256) void gemm_xw(const int* __restrict__ flags,
                                               const void* __restrict__ x_any,
                                               const ushort* __restrict__ wtg,
                                               const float* __restrict__ dis,
                                               ushort* __restrict__ hout) {
    __shared__ __align__(16) ushort wt[128 * 128];      // 32768 B
    const int f32f = flags[0];

    const int tid  = threadIdx.x;
    const int lane = tid & 63;
    const int quad = lane >> 4;
    const int lm   = lane & 15;
    const int wave = tid >> 6;

    const int rbase = blockIdx.x * 128 + wave * 32;
    int arow0 = rbase + lm;
    int arow1 = rbase + 16 + lm;
    if (arow0 >= N_NODES) arow0 = N_NODES - 1;    // clamp; store is guarded
    if (arow1 >= N_NODES) arow1 = N_NODES - 1;
    const float*  xrf0 = (const float*) x_any + (size_t)arow0 * F_IN;
    const float*  xrf1 = (const float*) x_any + (size_t)arow1 * F_IN;
    const ushort* xrb0 = (const ushort*)x_any + (size_t)arow0 * F_IN;
    const ushort* xrb1 = (const ushort*)x_any + (size_t)arow1 * F_IN;

    float4v acc0[8], acc1[8];
#pragma unroll
    for (int c = 0; c < 8; ++c) {
        acc0[c] = (float4v){0.f, 0.f, 0.f, 0.f};
        acc1[c] = (float4v){0.f, 0.f, 0.f, 0.f};
    }

    for (int hh = 0; hh < 2; ++hh) {
        if (hh) __syncthreads();
#pragma unroll
        for (int it = 0; it < 8; ++it) {
            int flat = (it * 256 + tid) * 8;       // ushort idx, 0..16376
            int col  = flat >> 7;
            int kloc = flat & 127;
            short8 v = *(const short8*)(wtg + col * F_IN + hh * 128 + kloc);
            int dst = ((col << 7) | kloc) ^ ((col & 7) << 3);
            *(short8*)(wt + dst) = v;
        }
        __syncthreads();
#pragma unroll
        for (int s = 0; s < 4; ++s) {
            int klocal = s * 32 + quad * 8;
            short8 afrag0, afrag1;
            if (f32f) {
                const float* p0 = xrf0 + hh * 128 + klocal;
                const float* p1 = xrf1 + hh * 128 + klocal;
                float4 u0 = *(const float4*)p0;
                float4 u1 = *(const float4*)(p0 + 4);
                float4 u2 = *(const float4*)p1;
                float4 u3 = *(const float4*)(p1 + 4);
                afrag0[0] = (short)f2b(u0.x); afrag0[1] = (short)f2b(u0.y);
                afrag0[2] = (short)f2b(u0.z); afrag0[3] = (short)f2b(u0.w);
                afrag0[4] = (short)f2b(u1.x); afrag0[5] = (short)f2b(u1.y);
                afrag0[6] = (short)f2b(u1.z); afrag0[7] = (short)f2b(u1.w);
                afrag1[0] = (short)f2b(u2.x); afrag1[1] = (short)f2b(u2.y);
                afrag1[2] = (short)f2b(u2.z); afrag1[3] = (short)f2b(u2.w);
                afrag1[4] = (short)f2b(u3.x); afrag1[5] = (short)f2b(u3.y);
                afrag1[6] = (short)f2b(u3.z); afrag1[7] = (short)f2b(u3.w);
            } else {
                afrag0 = *(const short8*)(xrb0 + hh * 128 + klocal);
                afrag1 = *(const short8*)(xrb1 + hh * 128 + klocal);
            }
#pragma unroll
            for (int c = 0; c < 8; ++c) {
                int colr = c * 16 + lm;
                int src = ((colr << 7) | klocal) ^ ((lm & 7) << 3);
                short8 bfrag = *(const short8*)(wt + src);
                acc0[c] = __builtin_amdgcn_mfma_f32_16x16x32_bf16(afrag0, bfrag, acc0[c], 0, 0, 0);
                acc1[c] = __builtin_amdgcn_mfma_f32_16x16x32_bf16(afrag1, bfrag, acc1[c], 0, 0, 0);
            }
        }
    }
    // D[row=quad*4+r][col=lane&15]; scale rows by dis[node] before rounding
    float dv0[4], dv1[4];
#pragma unroll
    for (int r = 0; r < 4; ++r) {
        int n0 = rbase + quad * 4 + r;
        int n1 = rbase + 16 + quad * 4 + r;
        dv0[r] = (n0 < N_NODES) ? dis[n0] : 0.f;
        dv1[r] = (n1 < N_NODES) ? dis[n1] : 0.f;
    }
#pragma unroll
    for (int c = 0; c < 8; ++c) {
        int col = c * 16 + lm;
#pragma unroll
        for (int r = 0; r < 4; ++r) {
            int n0 = rbase + quad * 4 + r;
            int n1 = rbase + 16 + quad * 4 + r;
            if (n0 < N_NODES) hout[(size_t)n0 * H_DIM + col] = f2b(acc0[c][r] * dv0[r]);
            if (n1 < N_NODES) hout[(size_t)n1 * H_DIM + col] = f2b(acc1[c][r] * dv1[r]);
        }
    }
}

// ------- FUSED: gather-reduce + bias/relu -> LDS -> bayes linear + lsm ------
// Block = 16 nodes. Gather phase: wave w handles nodes n0+4w..n0+4w+3
// sequentially (same wave-per-node work as before), a-rows staged in LDS
// (row pad +8 ushorts -> max 2-way bank aliasing, free per m136). Then one
// barrier and wave 0 runs the 8-MFMA logits + log_softmax for its 16 rows,
// storing out directly. Kills the 25.6MB aout write + 25.6MB re-read and
// the final_linear dispatch; final phase is ~1% of block time.
__global__ __launch_bounds__(256) void gather_final(const int* __restrict__ flags,
                                                    const int* __restrict__ offs,
                                                    const int* __restrict__ perm,
                                                    const float* __restrict__ dis,
                                                    const ushort* __restrict__ hb,
                                                    const float* __restrict__ gcnb_f,
                                                    const ushort* __restrict__ whi,
                                                    const ushort* __restrict__ wlo,
                                                    const float* __restrict__ bias16,
                                                    void* __restrict__ out) {
    __shared__ __align__(16) ushort alds[16][136];   // 4352 B, pad 8
    const int f32f = flags[0];
    const int lane = threadIdx.x & 63;
    const int wave = threadIdx.x >> 6;
    const int n0 = blockIdx.x * 16;                  // 16 | N_NODES

    // ---------------- gather phase: 4 nodes per wave, sequential ------------
    for (int r = 0; r < 4; ++r) {
        const int node = n0 + wave * 4 + r;
        const int off0 = __builtin_amdgcn_readfirstlane(offs[node]);
        const int deg  = __builtin_amdgcn_readfirstlane(offs[node + 1]) - off0;
        const int* pp = perm + off0;

        float ax = 0.f, ay = 0.f;
        const int full = deg & ~15;
        for (int base = 0; base < full; base += 16) {
#pragma unroll
            for (int k = 0; k < 16; ++k) {
                int sk = pp[base + k];              // scalar 4B load (uniform)
                uint u = *((const uint*)(hb + (size_t)sk * H_DIM) + lane);
                ax += __uint_as_float(u << 16);
                ay += __uint_as_float(u & 0xFFFF0000u);
            }
        }
        {
            const int nb = deg - full;              // 0..15, uniform
#pragma unroll
            for (int k = 0; k < 16; ++k) {
                int   sk = 0;
                float wk = 0.f;
                if (k < nb) { sk = pp[full + k]; wk = 1.f; }
                uint u = *((const uint*)(hb + (size_t)sk * H_DIM) + lane);
                ax = fmaf(wk, __uint_as_float(u << 16),         ax);
                ay = fmaf(wk, __uint_as_float(u & 0xFFFF0000u), ay);
            }
        }

        const float dd = dis[node];
        uint us = *((const uint*)(hb + (size_t)node * H_DIM) + lane); // h'[node]
        float2 gb = *(const float2*)(gcnb_f + 2 * lane);
        ax = (ax + __uint_as_float(us << 16))         * dd + gb.x;
        ay = (ay + __uint_as_float(us & 0xFFFF0000u)) * dd + gb.y;
        ax = fmaxf(ax, 0.f);
        ay = fmaxf(ay, 0.f);
        uint pack = (uint)f2b(ax) | ((uint)f2b(ay) << 16);
        *((uint*)&alds[wave * 4 + r][2 * lane]) = pack;
    }
    __syncthreads();
    if (wave != 0) return;

    // ---------------- final phase (wave 0): logits + log_softmax ------------
    const int lm = lane & 15, quad = lane >> 4;
    const ushort* bh = whi + lm * H_DIM + quad * 8;
    const ushort* bl = wlo + lm * H_DIM + quad * 8;

    float4v acc = (float4v){0.f, 0.f, 0.f, 0.f};
#pragma unroll
    for (int s = 0; s < 4; ++s) {
        short8 af = *(const short8*)&alds[lm][quad * 8 + s * 32];
        short8 b0 = *(const short8*)(bh + s * 32);
        short8 b1 = *(const short8*)(bl + s * 32);
        acc = __builtin_amdgcn_mfma_f32_16x16x32_bf16(af, b0, acc, 0, 0, 0);
        acc = __builtin_amdgcn_mfma_f32_16x16x32_bf16(af, b1, acc, 0, 0, 0);
    }

    const float bias = bias16[lm];
    float p[4], m[4], ss[4];
#pragma unroll
    for (int r = 0; r < 4; ++r) { p[r] = acc[r] + bias; m[r] = p[r]; }
#pragma unroll
    for (int off = 1; off < 16; off <<= 1)
#pragma unroll
        for (int r = 0; r < 4; ++r) m[r] = fmaxf(m[r], __shfl_xor(m[r], off, 64));
#pragma unroll
    for (int r = 0; r < 4; ++r) ss[r] = __expf(p[r] - m[r]);
#pragma unroll
    for (int off = 1; off < 16; off <<= 1)
#pragma unroll
        for (int r = 0; r < 4; ++r) ss[r] += __shfl_xor(ss[r], off, 64);

    if (f32f) {
        float* op = (float*)out;
#pragma unroll
        for (int r = 0; r < 4; ++r)
            op[(size_t)(n0 + quad * 4 + r) * C_CLS + lm] = p[r] - m[r] - __logf(ss[r]);
    } else {
        ushort* op = (ushort*)out;
#pragma unroll
        for (int r = 0; r < 4; ++r)
            op[(size_t)(n0 + quad * 4 + r) * C_CLS + lm] = f2b(p[r] - m[r] - __logf(ss[r]));
    }
}

// ---------------------------------------------------------------------------
extern "C" void kernel_launch(void* const* d_in, const int* in_sizes, int n_in,
                              void* d_out, int out_size, void* d_ws, size_t ws_size,
                              hipStream_t stream) {
    const int E = in_sizes[1] / 2;

    char* wp = (char*)d_ws;
    auto alloc = [&](size_t bytes) -> char* {
        char* p = wp; wp += (bytes + 511) & ~(size_t)511; return p;
    };
    int*    flags  = (int*)   alloc(64);
    ushort* hb     = (ushort*)alloc((size_t)N_NODES * H_DIM * 2);   // bf16 h*dis
    int*    cnt    = (int*)   alloc((size_t)N_NODES * 4);
    int*    offs   = (int*)   alloc((size_t)(N_NODES + 1) * 4);
    int*    cursor = (int*)   alloc((size_t)N_NODES * 4);
    int*    bsum   = (int*)   alloc((size_t)NB_SCAN * 4);
    int*    boff   = (int*)   alloc((size_t)NB_SCAN * 4);
    float*  dis    = (float*) alloc((size_t)N_NODES * 4);
    int*    perm   = (int*)   alloc((size_t)E * 4);                 // src only
    int2*   pr     = (int2*)  alloc((size_t)E * 8);                 // (s,d) compact
    ushort* wtg    = (ushort*)alloc((size_t)H_DIM * F_IN * 2);      // W^T bf16
    ushort* whi    = (ushort*)alloc((size_t)C_CLS * H_DIM * 2);
    ushort* wlo    = (ushort*)alloc((size_t)C_CLS * H_DIM * 2);
    float*  bias16 = (float*) alloc((size_t)C_CLS * 4);
    float*  gcnb_f = (float*) alloc((size_t)H_DIM * 4);

    sniff<<<1, 64, 0, stream>>>((const ushort*)d_in[0], (const int*)d_in[1], flags);
    prep_params<<<H_DIM + 1, 256, 0, stream>>>(flags, d_in[2], wtg,
                                  d_in[4], d_in[5], d_in[8],
                                  d_in[6], d_in[7], d_in[9], d_in[3],
                                  whi, wlo, bias16, gcnb_f);
    (void)hipMemsetAsync(cnt, 0, (size_t)N_NODES * 4, stream);
    prep<<<(E + 255) / 256, 256, 0, stream>>>(flags, (const int*)d_in[1], cnt, pr, E);
    scan1<<<NB_SCAN, 256, 0, stream>>>(cnt, offs, bsum);
    scan2<<<1, 512, 0, stream>>>(bsum, boff);
    scan3<<<NB_SCAN, 256, 0, stream>>>(offs, boff, cnt, cursor, dis, E);
    build_perm<<<2048, 256, 0, stream>>>(pr, cursor, perm, E);
    gemm_xw<<<(N_NODES + 127) / 128, 256, 0, stream>>>(flags, d_in[0], wtg, dis, hb);
    gather_final<<<N_NODES / 16, 256, 0, stream>>>(flags, offs, perm, dis, hb,
                                                   gcnb_f, whi, wlo, bias16, (void*)d_out);
}

// Round 12
// 376.185 us; speedup vs baseline: 1.6202x; 1.0770x over previous
//
#include <hip/hip_runtime.h>
#include <hip/hip_bf16.h>

#define N_NODES 100000
#define F_IN    256
#define H_DIM   128
#define C_CLS   16
#define NB_SCAN ((N_NODES + 255) / 256)   // 391
#define NSHARD  8
#define SHARD_W ((N_NODES + NSHARD - 1) / NSHARD)   // 12500
#define ZB      98                         // cnt-zeroing blocks (25000 int4 / 256)

typedef __attribute__((ext_vector_type(8))) short  short8;
typedef __attribute__((ext_vector_type(4))) float  float4v;
typedef __attribute__((ext_vector_type(4))) unsigned short ushort4v;

__device__ __forceinline__ float b2f(ushort u) {
    union { unsigned int i; float f; } v;
    v.i = ((unsigned int)u) << 16;
    return v.f;
}

__device__ __forceinline__ ushort f2b(float f) {
    unsigned int x = __float_as_uint(f);
    unsigned int r = (x + 0x7FFFu + ((x >> 16) & 1u)) >> 16;   // RNE
    return (ushort)r;
}

__device__ __forceinline__ float ldsel(const void* p, int i, int f32f) {
    return f32f ? ((const float*)p)[i] : b2f(((const ushort*)p)[i]);
}

// ------------------------------------------------------------------ sniff ---
__global__ __launch_bounds__(64) void sniff(const ushort* __restrict__ x,
                                            const int* __restrict__ ei,
                                            int* __restrict__ flags) {
    int lane = threadIdx.x;
    int cnt_bf = 0;
#pragma unroll
    for (int j = 0; j < 4; ++j) {
        ushort u = x[lane * 4 + j];
        int e = (u >> 7) & 0xFF;
        if ((e >= 100 && e <= 140) || (u & 0x7FFF) == 0) cnt_bf++;
    }
    int zodd = (ei[2 * lane + 1] == 0) ? 1 : 0;
#pragma unroll
    for (int off = 32; off >= 1; off >>= 1) {
        cnt_bf += __shfl_xor(cnt_bf, off, 64);
        zodd   += __shfl_xor(zodd,   off, 64);
    }
    if (lane == 0) {
        flags[0] = (cnt_bf < 230) ? 1 : 0;   // f32 inputs
        flags[1] = (zodd  >= 32) ? 1 : 0;    // int64 indices
    }
}

// -------- merged param prep: wtg = W^T + bayes weights + zero cnt -----------
// Blocks [0,128): wtg row n. Block 128: bayes weights/bias. Blocks >128:
// zero cnt (folds the hipMemsetAsync dispatch into this launch).
__global__ __launch_bounds__(256) void prep_params(const int* __restrict__ flags,
                                                   const void* __restrict__ W_any,
                                                   ushort* __restrict__ wtg,
                                                   const void* __restrict__ w_mu,
                                                   const void* __restrict__ w_ls,
                                                   const void* __restrict__ eps_w,
                                                   const void* __restrict__ b_mu,
                                                   const void* __restrict__ b_ls,
                                                   const void* __restrict__ eps_b,
                                                   const void* __restrict__ gcn_b,
                                                   ushort* __restrict__ whi,
                                                   ushort* __restrict__ wlo,
                                                   float* __restrict__ bias16,
                                                   float* __restrict__ gcnb_f,
                                                   int* __restrict__ cnt) {
    const int f32f = flags[0];
    const int t = threadIdx.x;
    if (blockIdx.x < H_DIM) {
        const int n = blockIdx.x;      // 0..127
        float v = f32f ? ((const float*)W_any)[t * H_DIM + n]
                       : b2f(((const ushort*)W_any)[t * H_DIM + n]);
        wtg[n * F_IN + t] = f2b(v);
        return;
    }
    if (blockIdx.x > H_DIM) {
        int idx4 = (blockIdx.x - H_DIM - 1) * 256 + t;   // int4 index
        if (idx4 < N_NODES / 4) ((int4*)cnt)[idx4] = make_int4(0, 0, 0, 0);
        return;
    }
#pragma unroll
    for (int i = t; i < C_CLS * H_DIM; i += 256) {
        float v = ldsel(w_mu, i, f32f) + __expf(ldsel(w_ls, i, f32f)) * ldsel(eps_w, i, f32f);
        ushort h = f2b(v);
        whi[i] = h;
        wlo[i] = f2b(v - b2f(h));     // residual: recovers ~16-bit mantissa
    }
    if (t < C_CLS)
        bias16[t] = ldsel(b_mu, t, f32f) + __expf(ldsel(b_ls, t, f32f)) * ldsel(eps_b, t, f32f);
    if (t < H_DIM)
        gcnb_f[t] = ldsel(gcn_b, t, f32f);
}

// ---- prep: compact (src,dst) + degree count + RANK (atomic return value) ---
// Round-11 insight: device-scope atomicAdd executes memory-side (the only
// cross-XCD coherence point) -- ~23G atomics/s, 39B/edge write traffic; the
// count is atomic-COUNT-bound. The add's return value IS the edge's rank
// within its dst, for free. Storing it makes the scatter pass atomic-free.
__global__ __launch_bounds__(256) void prep(const int* __restrict__ flags,
                                            const int* __restrict__ ei,
                                            int* __restrict__ cnt,
                                            int2* __restrict__ pr,
                                            int* __restrict__ rk, int E) {
    int e = blockIdx.x * 256 + threadIdx.x;
    if (e >= E) return;
    int i64 = flags[1];
    int s = i64 ? ei[2L * e]          : ei[e];
    int d = i64 ? ei[2L * E + 2L * e] : ei[(long)E + e];
    pr[e] = make_int2(s, d);
    rk[e] = atomicAdd(&cnt[d], 1);     // rank of e within dst d: 0..deg-1
}

// ------------------------------------------------------------ 2-step scan ---
__global__ __launch_bounds__(256) void scan1(const int* __restrict__ cnt,
                                             int* __restrict__ offs,
                                             int* __restrict__ bsum) {
    __shared__ int sd[256];
    int t = threadIdx.x;
    int i = blockIdx.x * 256 + t;
    int v = (i < N_NODES) ? cnt[i] : 0;
    sd[t] = v;
    __syncthreads();
#pragma unroll
    for (int d = 1; d < 256; d <<= 1) {
        int add = (t >= d) ? sd[t - d] : 0;
        __syncthreads();
        sd[t] += add;
        __syncthreads();
    }
    if (i < N_NODES) offs[i] = sd[t] - v;          // exclusive within block
    if (t == 255) bsum[blockIdx.x] = sd[255];
}

// merged scan2+scan3: each block reduces its OWN exclusive bsum prefix
// (<=391 values, 2 strided loads + wave/LDS reduce), then applies to its
// 256 nodes: global offs + dis. No cursor (scatter is atomic-free now).
__global__ __launch_bounds__(256) void scan23(int* __restrict__ offs,
                                              const int* __restrict__ bsum,
                                              const int* __restrict__ cnt,
                                              float* __restrict__ dis, int E) {
    __shared__ int ws[4];
    const int t = threadIdx.x;
    const int bid = blockIdx.x;
    const int lane = t & 63;
    const int wave = t >> 6;

    int acc = 0;
    for (int j = t; j < bid; j += 256) acc += bsum[j];
#pragma unroll
    for (int off = 32; off >= 1; off >>= 1) acc += __shfl_xor(acc, off, 64);
    if (lane == 0) ws[wave] = acc;
    __syncthreads();
    const int boffb = ws[0] + ws[1] + ws[2] + ws[3];

    int i = bid * 256 + t;
    if (i == 0) offs[N_NODES] = E;
    if (i >= N_NODES) return;
    offs[i] += boffb;
    dis[i] = rsqrtf((float)(cnt[i] + 1));          // +1 self-loop
}

// -------------------- ATOMIC-FREE sharded permutation scatter ---------------
// slot = offs[d] + rk[e] is a bijection by construction -- no cursor, no
// memory-side atomics. Static shard = blockIdx&7 keeps each XCD's perm
// window (~800KB) + offs slice (~50KB) L2-local; plain stores are
// write-back cached so dirty lines can accumulate all 16 slot-writes.
__global__ __launch_bounds__(256) void build_perm(const int2* __restrict__ pr,
                                                  const int* __restrict__ rk,
                                                  const int* __restrict__ offs,
                                                  int* __restrict__ perm, int E) {
    const int shard = blockIdx.x & (NSHARD - 1);
    const int jb    = blockIdx.x >> 3;
    const int nb    = gridDim.x >> 3;
    const int lo = shard * SHARD_W;
    const int hi = lo + SHARD_W;                 // N divides evenly
    for (int e = jb * 256 + threadIdx.x; e < E; e += nb * 256) {
        int2 p = pr[e];
        if (p.y >= lo && p.y < hi)
            perm[offs[p.y] + rk[e]] = p.x;
    }
}

// ------------------------------------------------- h' = (x @ W) * dis -------
// M=32 per wave (two A-frags share each B ds_read -> 2 MFMAs per b128 read).
// Block = 4 waves = 128 rows -> grid 782 <= resident blocks: no tail round.
// XOR-swizzled flat LDS: idx = ((col<<7)|k) ^ ((col&7)<<3).
__global__ __launch_bounds__(256) void gemm_xw(const int* __restrict__ flags,
                                               const void* __restrict__ x_any,
                                               const ushort* __restrict__ wtg,
                                               const float* __restrict__ dis,
                                               ushort* __restrict__ hout) {
    __shared__ __align__(16) ushort wt[128 * 128];      // 32768 B
    const int f32f = flags[0];

    const int tid  = threadIdx.x;
    const int lane = tid & 63;
    const int quad = lane >> 4;
    const int lm   = lane & 15;
    const int wave = tid >> 6;

    const int rbase = blockIdx.x * 128 + wave * 32;
    int arow0 = rbase + lm;
    int arow1 = rbase + 16 + lm;
    if (arow0 >= N_NODES) arow0 = N_NODES - 1;    // clamp; store is guarded
    if (arow1 >= N_NODES) arow1 = N_NODES - 1;
    const float*  xrf0 = (const float*) x_any + (size_t)arow0 * F_IN;
    const float*  xrf1 = (const float*) x_any + (size_t)arow1 * F_IN;
    const ushort* xrb0 = (const ushort*)x_any + (size_t)arow0 * F_IN;
    const ushort* xrb1 = (const ushort*)x_any + (size_t)arow1 * F_IN;

    float4v acc0[8], acc1[8];
#pragma unroll
    for (int c = 0; c < 8; ++c) {
        acc0[c] = (float4v){0.f, 0.f, 0.f, 0.f};
        acc1[c] = (float4v){0.f, 0.f, 0.f, 0.f};
    }

    for (int hh = 0; hh < 2; ++hh) {
        if (hh) __syncthreads();
#pragma unroll
        for (int it = 0; it < 8; ++it) {
            int flat = (it * 256 + tid) * 8;       // ushort idx, 0..16376
            int col  = flat >> 7;
            int kloc = flat & 127;
            short8 v = *(const short8*)(wtg + col * F_IN + hh * 128 + kloc);
            int dst = ((col << 7) | kloc) ^ ((col & 7) << 3);
            *(short8*)(wt + dst) = v;
        }
        __syncthreads();
#pragma unroll
        for (int s = 0; s < 4; ++s) {
            int klocal = s * 32 + quad * 8;
            short8 afrag0, afrag1;
            if (f32f) {
                const float* p0 = xrf0 + hh * 128 + klocal;
                const float* p1 = xrf1 + hh * 128 + klocal;
                float4 u0 = *(const float4*)p0;
                float4 u1 = *(const float4*)(p0 + 4);
                float4 u2 = *(const float4*)p1;
                float4 u3 = *(const float4*)(p1 + 4);
                afrag0[0] = (short)f2b(u0.x); afrag0[1] = (short)f2b(u0.y);
                afrag0[2] = (short)f2b(u0.z); afrag0[3] = (short)f2b(u0.w);
                afrag0[4] = (short)f2b(u1.x); afrag0[5] = (short)f2b(u1.y);
                afrag0[6] = (short)f2b(u1.z); afrag0[7] = (short)f2b(u1.w);
                afrag1[0] = (short)f2b(u2.x); afrag1[1] = (short)f2b(u2.y);
                afrag1[2] = (short)f2b(u2.z); afrag1[3] = (short)f2b(u2.w);
                afrag1[4] = (short)f2b(u3.x); afrag1[5] = (short)f2b(u3.y);
                afrag1[6] = (short)f2b(u3.z); afrag1[7] = (short)f2b(u3.w);
            } else {
                afrag0 = *(const short8*)(xrb0 + hh * 128 + klocal);
                afrag1 = *(const short8*)(xrb1 + hh * 128 + klocal);
            }
#pragma unroll
            for (int c = 0; c < 8; ++c) {
                int colr = c * 16 + lm;
                int src = ((colr << 7) | klocal) ^ ((lm & 7) << 3);
                short8 bfrag = *(const short8*)(wt + src);
                acc0[c] = __builtin_amdgcn_mfma_f32_16x16x32_bf16(afrag0, bfrag, acc0[c], 0, 0, 0);
                acc1[c] = __builtin_amdgcn_mfma_f32_16x16x32_bf16(afrag1, bfrag, acc1[c], 0, 0, 0);
            }
        }
    }
    // D[row=quad*4+r][col=lane&15]; scale rows by dis[node] before rounding
    float dv0[4], dv1[4];
#pragma unroll
    for (int r = 0; r < 4; ++r) {
        int n0 = rbase + quad * 4 + r;
        int n1 = rbase + 16 + quad * 4 + r;
        dv0[r] = (n0 < N_NODES) ? dis[n0] : 0.f;
        dv1[r] = (n1 < N_NODES) ? dis[n1] : 0.f;
    }
#pragma unroll
    for (int c = 0; c < 8; ++c) {
        int col = c * 16 + lm;
#pragma unroll
        for (int r = 0; r < 4; ++r) {
            int n0 = rbase + quad * 4 + r;
            int n1 = rbase + 16 + quad * 4 + r;
            if (n0 < N_NODES) hout[(size_t)n0 * H_DIM + col] = f2b(acc0[c][r] * dv0[r]);
            if (n1 < N_NODES) hout[(size_t)n1 * H_DIM + col] = f2b(acc1[c][r] * dv1[r]);
        }
    }
}

// ------- FUSED: gather-reduce + bias/relu -> LDS -> bayes linear + lsm ------
__global__ __launch_bounds__(256) void gather_final(const int* __restrict__ flags,
                                                    const int* __restrict__ offs,
                                                    const int* __restrict__ perm,
                                                    const float* __restrict__ dis,
                                                    const ushort* __restrict__ hb,
                                                    const float* __restrict__ gcnb_f,
                                                    const ushort* __restrict__ whi,
                                                    const ushort* __restrict__ wlo,
                                                    const float* __restrict__ bias16,
                                                    void* __restrict__ out) {
    __shared__ __align__(16) ushort alds[16][136];   // 4352 B, pad 8
    const int f32f = flags[0];
    const int lane = threadIdx.x & 63;
    const int wave = threadIdx.x >> 6;
    const int n0 = blockIdx.x * 16;                  // 16 | N_NODES

    // ---------------- gather phase: 4 nodes per wave, sequential ------------
    for (int r = 0; r < 4; ++r) {
        const int node = n0 + wave * 4 + r;
        const int off0 = __builtin_amdgcn_readfirstlane(offs[node]);
        const int deg  = __builtin_amdgcn_readfirstlane(offs[node + 1]) - off0;
        const int* pp = perm + off0;

        float ax = 0.f, ay = 0.f;
        const int full = deg & ~15;
        for (int base = 0; base < full; base += 16) {
#pragma unroll
            for (int k = 0; k < 16; ++k) {
                int sk = pp[base + k];              // scalar 4B load (uniform)
                uint u = *((const uint*)(hb + (size_t)sk * H_DIM) + lane);
                ax += __uint_as_float(u << 16);
                ay += __uint_as_float(u & 0xFFFF0000u);
            }
        }
        {
            const int nb = deg - full;              // 0..15, uniform
#pragma unroll
            for (int k = 0; k < 16; ++k) {
                int   sk = 0;
                float wk = 0.f;
                if (k < nb) { sk = pp[full + k]; wk = 1.f; }
                uint u = *((const uint*)(hb + (size_t)sk * H_DIM) + lane);
                ax = fmaf(wk, __uint_as_float(u << 16),         ax);
                ay = fmaf(wk, __uint_as_float(u & 0xFFFF0000u), ay);
            }
        }

        const float dd = dis[node];
        uint us = *((const uint*)(hb + (size_t)node * H_DIM) + lane); // h'[node]
        float2 gb = *(const float2*)(gcnb_f + 2 * lane);
        ax = (ax + __uint_as_float(us << 16))         * dd + gb.x;
        ay = (ay + __uint_as_float(us & 0xFFFF0000u)) * dd + gb.y;
        ax = fmaxf(ax, 0.f);
        ay = fmaxf(ay, 0.f);
        uint pack = (uint)f2b(ax) | ((uint)f2b(ay) << 16);
        *((uint*)&alds[wave * 4 + r][2 * lane]) = pack;
    }
    __syncthreads();
    if (wave != 0) return;

    // ---------------- final phase (wave 0): logits + log_softmax ------------
    const int lm = lane & 15, quad = lane >> 4;
    const ushort* bh = whi + lm * H_DIM + quad * 8;
    const ushort* bl = wlo + lm * H_DIM + quad * 8;

    float4v acc = (float4v){0.f, 0.f, 0.f, 0.f};
#pragma unroll
    for (int s = 0; s < 4; ++s) {
        short8 af = *(const short8*)&alds[lm][quad * 8 + s * 32];
        short8 b0 = *(const short8*)(bh + s * 32);
        short8 b1 = *(const short8*)(bl + s * 32);
        acc = __builtin_amdgcn_mfma_f32_16x16x32_bf16(af, b0, acc, 0, 0, 0);
        acc = __builtin_amdgcn_mfma_f32_16x16x32_bf16(af, b1, acc, 0, 0, 0);
    }

    const float bias = bias16[lm];
    float p[4], m[4], ss[4];
#pragma unroll
    for (int r = 0; r < 4; ++r) { p[r] = acc[r] + bias; m[r] = p[r]; }
#pragma unroll
    for (int off = 1; off < 16; off <<= 1)
#pragma unroll
        for (int r = 0; r < 4; ++r) m[r] = fmaxf(m[r], __shfl_xor(m[r], off, 64));
#pragma unroll
    for (int r = 0; r < 4; ++r) ss[r] = __expf(p[r] - m[r]);
#pragma unroll
    for (int off = 1; off < 16; off <<= 1)
#pragma unroll
        for (int r = 0; r < 4; ++r) ss[r] += __shfl_xor(ss[r], off, 64);

    if (f32f) {
        float* op = (float*)out;
#pragma unroll
        for (int r = 0; r < 4; ++r)
            op[(size_t)(n0 + quad * 4 + r) * C_CLS + lm] = p[r] - m[r] - __logf(ss[r]);
    } else {
        ushort* op = (ushort*)out;
#pragma unroll
        for (int r = 0; r < 4; ++r)
            op[(size_t)(n0 + quad * 4 + r) * C_CLS + lm] = f2b(p[r] - m[r] - __logf(ss[r]));
    }
}

// ---------------------------------------------------------------------------
extern "C" void kernel_launch(void* const* d_in, const int* in_sizes, int n_in,
                              void* d_out, int out_size, void* d_ws, size_t ws_size,
                              hipStream_t stream) {
    const int E = in_sizes[1] / 2;

    char* wp = (char*)d_ws;
    auto alloc = [&](size_t bytes) -> char* {
        char* p = wp; wp += (bytes + 511) & ~(size_t)511; return p;
    };
    int*    flags  = (int*)   alloc(64);
    ushort* hb     = (ushort*)alloc((size_t)N_NODES * H_DIM * 2);   // bf16 h*dis
    int*    cnt    = (int*)   alloc((size_t)N_NODES * 4);
    int*    offs   = (int*)   alloc((size_t)(N_NODES + 1) * 4);
    int*    bsum   = (int*)   alloc((size_t)NB_SCAN * 4);
    float*  dis    = (float*) alloc((size_t)N_NODES * 4);
    int*    perm   = (int*)   alloc((size_t)E * 4);                 // src only
    int2*   pr     = (int2*)  alloc((size_t)E * 8);                 // (s,d) compact
    int*    rk     = (int*)   alloc((size_t)E * 4);                 // edge rank in dst
    ushort* wtg    = (ushort*)alloc((size_t)H_DIM * F_IN * 2);      // W^T bf16
    ushort* whi    = (ushort*)alloc((size_t)C_CLS * H_DIM * 2);
    ushort* wlo    = (ushort*)alloc((size_t)C_CLS * H_DIM * 2);
    float*  bias16 = (float*) alloc((size_t)C_CLS * 4);
    float*  gcnb_f = (float*) alloc((size_t)H_DIM * 4);

    sniff<<<1, 64, 0, stream>>>((const ushort*)d_in[0], (const int*)d_in[1], flags);
    prep_params<<<H_DIM + 1 + ZB, 256, 0, stream>>>(flags, d_in[2], wtg,
                                  d_in[4], d_in[5], d_in[8],
                                  d_in[6], d_in[7], d_in[9], d_in[3],
                                  whi, wlo, bias16, gcnb_f, cnt);
    prep<<<(E + 255) / 256, 256, 0, stream>>>(flags, (const int*)d_in[1], cnt, pr, rk, E);
    scan1<<<NB_SCAN, 256, 0, stream>>>(cnt, offs, bsum);
    scan23<<<NB_SCAN, 256, 0, stream>>>(offs, bsum, cnt, dis, E);
    build_perm<<<2048, 256, 0, stream>>>(pr, rk, offs, perm, E);
    gemm_xw<<<(N_NODES + 127) / 128, 256, 0, stream>>>(flags, d_in[0], wtg, dis, hb);
    gather_final<<<N_NODES / 16, 256, 0, stream>>>(flags, offs, perm, dis, hb,
                                                   gcnb_f, whi, wlo, bias16, (void*)d_out);
}

// Round 13
// 361.759 us; speedup vs baseline: 1.6848x; 1.0399x over previous
//
#include <hip/hip_runtime.h>
#include <hip/hip_bf16.h>

#define N_NODES 100000
#define F_IN    256
#define H_DIM   128
#define C_CLS   16
#define NSHARD  8
#define SHARD_W ((N_NODES + NSHARD - 1) / NSHARD)   // 12500
#define MAXDEG  64                                  // ELL row width; deg~Poisson(16)
#define ZB      98                                  // cnt-zeroing blocks

typedef __attribute__((ext_vector_type(8))) short  short8;
typedef __attribute__((ext_vector_type(4))) float  float4v;
typedef __attribute__((ext_vector_type(4))) unsigned short ushort4v;

__device__ __forceinline__ float b2f(ushort u) {
    union { unsigned int i; float f; } v;
    v.i = ((unsigned int)u) << 16;
    return v.f;
}

__device__ __forceinline__ ushort f2b(float f) {
    unsigned int x = __float_as_uint(f);
    unsigned int r = (x + 0x7FFFu + ((x >> 16) & 1u)) >> 16;   // RNE
    return (ushort)r;
}

__device__ __forceinline__ float ldsel(const void* p, int i, int f32f) {
    return f32f ? ((const float*)p)[i] : b2f(((const ushort*)p)[i]);
}

// ------------------------------------------------------------------ sniff ---
__global__ __launch_bounds__(64) void sniff(const ushort* __restrict__ x,
                                            const int* __restrict__ ei,
                                            int* __restrict__ flags) {
    int lane = threadIdx.x;
    int cnt_bf = 0;
#pragma unroll
    for (int j = 0; j < 4; ++j) {
        ushort u = x[lane * 4 + j];
        int e = (u >> 7) & 0xFF;
        if ((e >= 100 && e <= 140) || (u & 0x7FFF) == 0) cnt_bf++;
    }
    int zodd = (ei[2 * lane + 1] == 0) ? 1 : 0;
#pragma unroll
    for (int off = 32; off >= 1; off >>= 1) {
        cnt_bf += __shfl_xor(cnt_bf, off, 64);
        zodd   += __shfl_xor(zodd,   off, 64);
    }
    if (lane == 0) {
        flags[0] = (cnt_bf < 230) ? 1 : 0;   // f32 inputs
        flags[1] = (zodd  >= 32) ? 1 : 0;    // int64 indices
    }
}

// -------- merged param prep: wtg = W^T + bayes weights + zero cnt/ocnt ------
__global__ __launch_bounds__(256) void prep_params(const int* __restrict__ flags,
                                                   const void* __restrict__ W_any,
                                                   ushort* __restrict__ wtg,
                                                   const void* __restrict__ w_mu,
                                                   const void* __restrict__ w_ls,
                                                   const void* __restrict__ eps_w,
                                                   const void* __restrict__ b_mu,
                                                   const void* __restrict__ b_ls,
                                                   const void* __restrict__ eps_b,
                                                   const void* __restrict__ gcn_b,
                                                   ushort* __restrict__ whi,
                                                   ushort* __restrict__ wlo,
                                                   float* __restrict__ bias16,
                                                   float* __restrict__ gcnb_f,
                                                   int* __restrict__ cnt,
                                                   int* __restrict__ ocnt) {
    const int f32f = flags[0];
    const int t = threadIdx.x;
    if (blockIdx.x < H_DIM) {
        const int n = blockIdx.x;      // 0..127
        float v = f32f ? ((const float*)W_any)[t * H_DIM + n]
                       : b2f(((const ushort*)W_any)[t * H_DIM + n]);
        wtg[n * F_IN + t] = f2b(v);
        return;
    }
    if (blockIdx.x > H_DIM) {
        int idx4 = (blockIdx.x - H_DIM - 1) * 256 + t;   // int4 index
        if (idx4 < N_NODES / 4) ((int4*)cnt)[idx4] = make_int4(0, 0, 0, 0);
        return;
    }
    if (t == 0) *ocnt = 0;
#pragma unroll
    for (int i = t; i < C_CLS * H_DIM; i += 256) {
        float v = ldsel(w_mu, i, f32f) + __expf(ldsel(w_ls, i, f32f)) * ldsel(eps_w, i, f32f);
        ushort h = f2b(v);
        whi[i] = h;
        wlo[i] = f2b(v - b2f(h));     // residual: recovers ~16-bit mantissa
    }
    if (t < C_CLS)
        bias16[t] = ldsel(b_mu, t, f32f) + __expf(ldsel(b_ls, t, f32f)) * ldsel(eps_b, t, f32f);
    if (t < H_DIM)
        gcnb_f[t] = ldsel(gcn_b, t, f32f);
}

// ---------------- ONE-PASS count + rank + ELL scatter (XCD-sharded) ---------
// Round-12 collapse: the atomic's returned rank is used IMMEDIATELY as the
// slot (slot = d*MAXDEG + rk), so the CSR prefix-scan and the pr/rk
// intermediates (19.2MB write + 19.2MB read) disappear. Structure is
// round-8's proven 71us scatter: shard = blockIdx&7, dst-filtered rescans
// of ei (L3-resident), writes confined to a 3.2MB/XCD ELL window + 50KB
// cnt slice. Rare rk>=MAXDEG edges (P~e^-40 at Poisson(16), but input-
// agnostic correctness) spill to an overflow list handled in gather.
__global__ __launch_bounds__(256) void ell_scatter(const int* __restrict__ flags,
                                                   const int* __restrict__ ei,
                                                   int* __restrict__ cnt,
                                                   int* __restrict__ ell,
                                                   int2* __restrict__ ovf,
                                                   int* __restrict__ ocnt, int E) {
    const int shard = blockIdx.x & (NSHARD - 1);
    const int jb    = blockIdx.x >> 3;
    const int nb    = gridDim.x >> 3;
    const int lo = shard * SHARD_W;
    const int hi = lo + SHARD_W;                 // N divides evenly
    const int i64 = flags[1];
    for (long e = (long)jb * 256 + threadIdx.x; e < E; e += (long)nb * 256) {
        int d = i64 ? ei[2L * E + 2L * e] : ei[(long)E + e];
        if (d >= lo && d < hi) {
            int s = i64 ? ei[2L * e] : ei[e];
            int rk = atomicAdd(&cnt[d], 1);
            if (rk < MAXDEG) ell[(long)d * MAXDEG + rk] = s;
            else { int oi = atomicAdd(ocnt, 1); ovf[oi] = make_int2(s, d); }
        }
    }
}

// ------------------------------- h' = (x @ W) * rsqrt(deg+1) ----------------
// M=32 per wave; XOR-swizzled flat LDS: idx = ((col<<7)|k) ^ ((col&7)<<3).
// dis computed inline from cnt (no dis buffer / scan dependency).
__global__ __launch_bounds__(256) void gemm_xw(const int* __restrict__ flags,
                                               const void* __restrict__ x_any,
                                               const ushort* __restrict__ wtg,
                                               const int* __restrict__ cnt,
                                               ushort* __restrict__ hout) {
    __shared__ __align__(16) ushort wt[128 * 128];      // 32768 B
    const int f32f = flags[0];

    const int tid  = threadIdx.x;
    const int lane = tid & 63;
    const int quad = lane >> 4;
    const int lm   = lane & 15;
    const int wave = tid >> 6;

    const int rbase = blockIdx.x * 128 + wave * 32;
    int arow0 = rbase + lm;
    int arow1 = rbase + 16 + lm;
    if (arow0 >= N_NODES) arow0 = N_NODES - 1;    // clamp; store is guarded
    if (arow1 >= N_NODES) arow1 = N_NODES - 1;
    const float*  xrf0 = (const float*) x_any + (size_t)arow0 * F_IN;
    const float*  xrf1 = (const float*) x_any + (size_t)arow1 * F_IN;
    const ushort* xrb0 = (const ushort*)x_any + (size_t)arow0 * F_IN;
    const ushort* xrb1 = (const ushort*)x_any + (size_t)arow1 * F_IN;

    float4v acc0[8], acc1[8];
#pragma unroll
    for (int c = 0; c < 8; ++c) {
        acc0[c] = (float4v){0.f, 0.f, 0.f, 0.f};
        acc1[c] = (float4v){0.f, 0.f, 0.f, 0.f};
    }

    for (int hh = 0; hh < 2; ++hh) {
        if (hh) __syncthreads();
#pragma unroll
        for (int it = 0; it < 8; ++it) {
            int flat = (it * 256 + tid) * 8;       // ushort idx, 0..16376
            int col  = flat >> 7;
            int kloc = flat & 127;
            short8 v = *(const short8*)(wtg + col * F_IN + hh * 128 + kloc);
            int dst = ((col << 7) | kloc) ^ ((col & 7) << 3);
            *(short8*)(wt + dst) = v;
        }
        __syncthreads();
#pragma unroll
        for (int s = 0; s < 4; ++s) {
            int klocal = s * 32 + quad * 8;
            short8 afrag0, afrag1;
            if (f32f) {
                const float* p0 = xrf0 + hh * 128 + klocal;
                const float* p1 = xrf1 + hh * 128 + klocal;
                float4 u0 = *(const float4*)p0;
                float4 u1 = *(const float4*)(p0 + 4);
                float4 u2 = *(const float4*)p1;
                float4 u3 = *(const float4*)(p1 + 4);
                afrag0[0] = (short)f2b(u0.x); afrag0[1] = (short)f2b(u0.y);
                afrag0[2] = (short)f2b(u0.z); afrag0[3] = (short)f2b(u0.w);
                afrag0[4] = (short)f2b(u1.x); afrag0[5] = (short)f2b(u1.y);
                afrag0[6] = (short)f2b(u1.z); afrag0[7] = (short)f2b(u1.w);
                afrag1[0] = (short)f2b(u2.x); afrag1[1] = (short)f2b(u2.y);
                afrag1[2] = (short)f2b(u2.z); afrag1[3] = (short)f2b(u2.w);
                afrag1[4] = (short)f2b(u3.x); afrag1[5] = (short)f2b(u3.y);
                afrag1[6] = (short)f2b(u3.z); afrag1[7] = (short)f2b(u3.w);
            } else {
                afrag0 = *(const short8*)(xrb0 + hh * 128 + klocal);
                afrag1 = *(const short8*)(xrb1 + hh * 128 + klocal);
            }
#pragma unroll
            for (int c = 0; c < 8; ++c) {
                int colr = c * 16 + lm;
                int src = ((colr << 7) | klocal) ^ ((lm & 7) << 3);
                short8 bfrag = *(const short8*)(wt + src);
                acc0[c] = __builtin_amdgcn_mfma_f32_16x16x32_bf16(afrag0, bfrag, acc0[c], 0, 0, 0);
                acc1[c] = __builtin_amdgcn_mfma_f32_16x16x32_bf16(afrag1, bfrag, acc1[c], 0, 0, 0);
            }
        }
    }
    // D[row=quad*4+r][col=lane&15]; scale rows by rsqrt(deg+1) before rounding
    float dv0[4], dv1[4];
#pragma unroll
    for (int r = 0; r < 4; ++r) {
        int n0 = rbase + quad * 4 + r;
        int n1 = rbase + 16 + quad * 4 + r;
        dv0[r] = (n0 < N_NODES) ? rsqrtf((float)(cnt[n0] + 1)) : 0.f;
        dv1[r] = (n1 < N_NODES) ? rsqrtf((float)(cnt[n1] + 1)) : 0.f;
    }
#pragma unroll
    for (int c = 0; c < 8; ++c) {
        int col = c * 16 + lm;
#pragma unroll
        for (int r = 0; r < 4; ++r) {
            int n0 = rbase + quad * 4 + r;
            int n1 = rbase + 16 + quad * 4 + r;
            if (n0 < N_NODES) hout[(size_t)n0 * H_DIM + col] = f2b(acc0[c][r] * dv0[r]);
            if (n1 < N_NODES) hout[(size_t)n1 * H_DIM + col] = f2b(acc1[c][r] * dv1[r]);
        }
    }
}

// ------- FUSED: ELL gather + bias/relu -> LDS -> bayes linear + lsm ---------
// Block = 16 nodes; wave w gathers nodes n0+4w..+3 from its ELL rows
// (base = node*MAXDEG, deg = cnt[node]); rare deg>MAXDEG nodes also scan
// the tiny overflow list. dis = rsqrt(deg+1) inline. Then wave 0 runs the
// 8-MFMA logits + log_softmax and stores out directly.
__global__ __launch_bounds__(256) void gather_final(const int* __restrict__ flags,
                                                    const int* __restrict__ cnt,
                                                    const int* __restrict__ ell,
                                                    const int2* __restrict__ ovf,
                                                    const int* __restrict__ ocnt,
                                                    const ushort* __restrict__ hb,
                                                    const float* __restrict__ gcnb_f,
                                                    const ushort* __restrict__ whi,
                                                    const ushort* __restrict__ wlo,
                                                    const float* __restrict__ bias16,
                                                    void* __restrict__ out) {
    __shared__ __align__(16) ushort alds[16][136];   // 4352 B, pad 8
    const int f32f = flags[0];
    const int lane = threadIdx.x & 63;
    const int wave = threadIdx.x >> 6;
    const int n0 = blockIdx.x * 16;                  // 16 | N_NODES

    // ---------------- gather phase: 4 nodes per wave, sequential ------------
    for (int r = 0; r < 4; ++r) {
        const int node = n0 + wave * 4 + r;
        const int degt = __builtin_amdgcn_readfirstlane(cnt[node]);
        const int deg  = degt < MAXDEG ? degt : MAXDEG;
        const int* pp = ell + (long)node * MAXDEG;

        float ax = 0.f, ay = 0.f;
        const int full = deg & ~15;
        for (int base = 0; base < full; base += 16) {
#pragma unroll
            for (int k = 0; k < 16; ++k) {
                int sk = pp[base + k];              // scalar 4B load (uniform)
                uint u = *((const uint*)(hb + (size_t)sk * H_DIM) + lane);
                ax += __uint_as_float(u << 16);
                ay += __uint_as_float(u & 0xFFFF0000u);
            }
        }
        {
            const int nb = deg - full;              // 0..15, uniform
#pragma unroll
            for (int k = 0; k < 16; ++k) {
                int   sk = 0;
                float wk = 0.f;
                if (k < nb) { sk = pp[full + k]; wk = 1.f; }
                uint u = *((const uint*)(hb + (size_t)sk * H_DIM) + lane);
                ax = fmaf(wk, __uint_as_float(u << 16),         ax);
                ay = fmaf(wk, __uint_as_float(u & 0xFFFF0000u), ay);
            }
        }
        if (degt > MAXDEG) {                        // rare: scan overflow list
            const int no = __builtin_amdgcn_readfirstlane(*ocnt);
            for (int j = 0; j < no; ++j) {
                int2 o = ovf[j];
                if (o.y == node) {
                    uint u = *((const uint*)(hb + (size_t)o.x * H_DIM) + lane);
                    ax += __uint_as_float(u << 16);
                    ay += __uint_as_float(u & 0xFFFF0000u);
                }
            }
        }

        const float dd = rsqrtf((float)(degt + 1));
        uint us = *((const uint*)(hb + (size_t)node * H_DIM) + lane); // h'[node]
        float2 gb = *(const float2*)(gcnb_f + 2 * lane);
        ax = (ax + __uint_as_float(us << 16))         * dd + gb.x;
        ay = (ay + __uint_as_float(us & 0xFFFF0000u)) * dd + gb.y;
        ax = fmaxf(ax, 0.f);
        ay = fmaxf(ay, 0.f);
        uint pack = (uint)f2b(ax) | ((uint)f2b(ay) << 16);
        *((uint*)&alds[wave * 4 + r][2 * lane]) = pack;
    }
    __syncthreads();
    if (wave != 0) return;

    // ---------------- final phase (wave 0): logits + log_softmax ------------
    const int lm = lane & 15, quad = lane >> 4;
    const ushort* bh = whi + lm * H_DIM + quad * 8;
    const ushort* bl = wlo + lm * H_DIM + quad * 8;

    float4v acc = (float4v){0.f, 0.f, 0.f, 0.f};
#pragma unroll
    for (int s = 0; s < 4; ++s) {
        short8 af = *(const short8*)&alds[lm][quad * 8 + s * 32];
        short8 b0 = *(const short8*)(bh + s * 32);
        short8 b1 = *(const short8*)(bl + s * 32);
        acc = __builtin_amdgcn_mfma_f32_16x16x32_bf16(af, b0, acc, 0, 0, 0);
        acc = __builtin_amdgcn_mfma_f32_16x16x32_bf16(af, b1, acc, 0, 0, 0);
    }

    const float bias = bias16[lm];
    float p[4], m[4], ss[4];
#pragma unroll
    for (int r = 0; r < 4; ++r) { p[r] = acc[r] + bias; m[r] = p[r]; }
#pragma unroll
    for (int off = 1; off < 16; off <<= 1)
#pragma unroll
        for (int r = 0; r < 4; ++r) m[r] = fmaxf(m[r], __shfl_xor(m[r], off, 64));
#pragma unroll
    for (int r = 0; r < 4; ++r) ss[r] = __expf(p[r] - m[r]);
#pragma unroll
    for (int off = 1; off < 16; off <<= 1)
#pragma unroll
        for (int r = 0; r < 4; ++r) ss[r] += __shfl_xor(ss[r], off, 64);

    if (f32f) {
        float* op = (float*)out;
#pragma unroll
        for (int r = 0; r < 4; ++r)
            op[(size_t)(n0 + quad * 4 + r) * C_CLS + lm] = p[r] - m[r] - __logf(ss[r]);
    } else {
        ushort* op = (ushort*)out;
#pragma unroll
        for (int r = 0; r < 4; ++r)
            op[(size_t)(n0 + quad * 4 + r) * C_CLS + lm] = f2b(p[r] - m[r] - __logf(ss[r]));
    }
}

// ---------------------------------------------------------------------------
extern "C" void kernel_launch(void* const* d_in, const int* in_sizes, int n_in,
                              void* d_out, int out_size, void* d_ws, size_t ws_size,
                              hipStream_t stream) {
    const int E = in_sizes[1] / 2;

    char* wp = (char*)d_ws;
    auto alloc = [&](size_t bytes) -> char* {
        char* p = wp; wp += (bytes + 511) & ~(size_t)511; return p;
    };
    int*    flags  = (int*)   alloc(64);
    ushort* hb     = (ushort*)alloc((size_t)N_NODES * H_DIM * 2);   // bf16 h*dis
    int*    cnt    = (int*)   alloc((size_t)N_NODES * 4);
    int*    ell    = (int*)   alloc((size_t)N_NODES * MAXDEG * 4);  // 25.6 MB
    int2*   ovf    = (int2*)  alloc((size_t)E * 8);                 // overflow (rare)
    int*    ocnt   = (int*)   alloc(64);
    ushort* wtg    = (ushort*)alloc((size_t)H_DIM * F_IN * 2);      // W^T bf16
    ushort* whi    = (ushort*)alloc((size_t)C_CLS * H_DIM * 2);
    ushort* wlo    = (ushort*)alloc((size_t)C_CLS * H_DIM * 2);
    float*  bias16 = (float*) alloc((size_t)C_CLS * 4);
    float*  gcnb_f = (float*) alloc((size_t)H_DIM * 4);

    sniff<<<1, 64, 0, stream>>>((const ushort*)d_in[0], (const int*)d_in[1], flags);
    prep_params<<<H_DIM + 1 + ZB, 256, 0, stream>>>(flags, d_in[2], wtg,
                                  d_in[4], d_in[5], d_in[8],
                                  d_in[6], d_in[7], d_in[9], d_in[3],
                                  whi, wlo, bias16, gcnb_f, cnt, ocnt);
    ell_scatter<<<2048, 256, 0, stream>>>(flags, (const int*)d_in[1], cnt, ell, ovf, ocnt, E);
    gemm_xw<<<(N_NODES + 127) / 128, 256, 0, stream>>>(flags, d_in[0], wtg, cnt, hb);
    gather_final<<<N_NODES / 16, 256, 0, stream>>>(flags, cnt, ell, ovf, ocnt, hb,
                                                   gcnb_f, whi, wlo, bias16, (void*)d_out);
}